// Round 6
// baseline (5447.012 us; speedup 1.0000x reference)
//
#include <hip/hip_runtime.h>
#include <hip/hip_bf16.h>

#define S 2048
#define NEGV -10000.0f

typedef unsigned long long ull;
typedef unsigned int uint4v __attribute__((ext_vector_type(4)));

__device__ __forceinline__ float fsig(float x) {
  return 1.0f / (1.0f + __expf(-x));
}
__device__ __forceinline__ float ftanh(float x) {
  float a = fabsf(x);
  float e = __expf(-2.0f * a);
  float r = (1.0f - e) / (1.0f + e);
  return copysignf(r, x);
}

// ---------------- init: seed h0 with stamp 1, invalidate other slot ----------------
__global__ void init_h_k(const float* __restrict__ h0, ull* __restrict__ hbuf) {
  int dir = blockIdx.x;          // 0,1
  int u = threadIdx.x;           // 0..511
  ull pk = (1ULL << 32) | (ull)__float_as_uint(h0[dir * 512 + u]);
  __hip_atomic_store(&hbuf[dir * 1024 + u], pk, __ATOMIC_RELAXED, __HIP_MEMORY_SCOPE_AGENT);
  __hip_atomic_store(&hbuf[dir * 1024 + 512 + u], 0ULL, __ATOMIC_RELAXED, __HIP_MEMORY_SCOPE_AGENT);
}

// ---------------- xg GEMM: xg[m][n] = emb[sent[m]] . Wrow(n) + bias(n) ----------------
__global__ __launch_bounds__(256) void gemm_xg_k(
    const int* __restrict__ sent, const float* __restrict__ emb,
    const float* __restrict__ Wih_f, const float* __restrict__ Wih_b,
    const float* __restrict__ bih_f, const float* __restrict__ bhh_f,
    const float* __restrict__ bih_b, const float* __restrict__ bhh_b,
    float* __restrict__ xg)
{
  __shared__ __align__(16) float Asm[64 * 36];   // [64][36] pad
  __shared__ __align__(16) float Bsm[32 * 68];   // [32][68] pad, B[kk][n]
  __shared__ int sidx[64];

  const int bx = blockIdx.x;     // N tile 0..63
  const int by = blockIdx.y;     // M tile 0..31
  const int t = threadIdx.x;
  const int n0 = bx * 64, m0 = by * 64;

  const float* W = (n0 < 2048) ? (Wih_f + (size_t)n0 * 1024)
                               : (Wih_b + (size_t)(n0 - 2048) * 1024);
  if (t < 64) sidx[t] = sent[m0 + t];
  __syncthreads();

  const int tm = t >> 4, tn = t & 15;
  const int lr = t >> 2, lkq = t & 3;   // loader: row, k-quarter (8 floats)
  float acc[4][4] = {};

  for (int k0 = 0; k0 < 1024; k0 += 32) {
    const float* ap = emb + (size_t)sidx[lr] * 1024 + k0 + lkq * 8;
    float4 a0 = *(const float4*)ap;
    float4 a1 = *(const float4*)(ap + 4);
    const float* bp = W + (size_t)lr * 1024 + k0 + lkq * 8;
    float4 b0 = *(const float4*)bp;
    float4 b1 = *(const float4*)(bp + 4);
    __syncthreads();   // prior compute done before LDS overwrite
    *(float4*)&Asm[lr * 36 + lkq * 8]     = a0;
    *(float4*)&Asm[lr * 36 + lkq * 8 + 4] = a1;
    {
      const float* bb0 = (const float*)&b0;
      const float* bb1 = (const float*)&b1;
      #pragma unroll
      for (int j = 0; j < 4; ++j) Bsm[(lkq * 8 + j) * 68 + lr] = bb0[j];
      #pragma unroll
      for (int j = 0; j < 4; ++j) Bsm[(lkq * 8 + 4 + j) * 68 + lr] = bb1[j];
    }
    __syncthreads();
    #pragma unroll
    for (int kk = 0; kk < 32; ++kk) {
      float a0_ = Asm[(tm * 4 + 0) * 36 + kk];
      float a1_ = Asm[(tm * 4 + 1) * 36 + kk];
      float a2_ = Asm[(tm * 4 + 2) * 36 + kk];
      float a3_ = Asm[(tm * 4 + 3) * 36 + kk];
      float4 bv = *(const float4*)&Bsm[kk * 68 + tn * 4];
      acc[0][0] = fmaf(a0_, bv.x, acc[0][0]); acc[0][1] = fmaf(a0_, bv.y, acc[0][1]);
      acc[0][2] = fmaf(a0_, bv.z, acc[0][2]); acc[0][3] = fmaf(a0_, bv.w, acc[0][3]);
      acc[1][0] = fmaf(a1_, bv.x, acc[1][0]); acc[1][1] = fmaf(a1_, bv.y, acc[1][1]);
      acc[1][2] = fmaf(a1_, bv.z, acc[1][2]); acc[1][3] = fmaf(a1_, bv.w, acc[1][3]);
      acc[2][0] = fmaf(a2_, bv.x, acc[2][0]); acc[2][1] = fmaf(a2_, bv.y, acc[2][1]);
      acc[2][2] = fmaf(a2_, bv.z, acc[2][2]); acc[2][3] = fmaf(a2_, bv.w, acc[2][3]);
      acc[3][0] = fmaf(a3_, bv.x, acc[3][0]); acc[3][1] = fmaf(a3_, bv.y, acc[3][1]);
      acc[3][2] = fmaf(a3_, bv.z, acc[3][2]); acc[3][3] = fmaf(a3_, bv.w, acc[3][3]);
    }
  }

  const float* bi = (n0 < 2048) ? bih_f : bih_b;
  const float* bh = (n0 < 2048) ? bhh_f : bhh_b;
  const int nb = (n0 < 2048) ? n0 : (n0 - 2048);
  #pragma unroll
  for (int i = 0; i < 4; ++i) {
    int m = m0 + tm * 4 + i;
    #pragma unroll
    for (int j = 0; j < 4; ++j) {
      int nn = tn * 4 + j;
      float bias = bi[nb + nn] + bh[nb + nn];
      xg[(size_t)m * 4096 + n0 + nn] = acc[i][j] + bias;
    }
  }
}

// ---------------- persistent bidirectional LSTM recurrence ----------------
// 128 WGs x 320 thr (4 compute waves + 1 service wave). dir=wg&1, wid=wg>>1
// owns units wid*8..+7. WAVE ROLE SPLIT (vmcnt is per-wave!):
//  - compute waves (t<256): ONLY vmem = 16B poll loads -> vmcnt(0) in the
//    poll loop is exact. Poll h_k (stamp k+1, slot k&1), stage to padded LDS,
//    barrier, 64-wide dot, shfl-reduce, write 32 row-sums + flags to LDS.
//  - service wave (t>=256): xg prefetch (2-step pipeline), spins on LDS flags
//    (no vmem), adds xg, activates, publishes stamped h + archives hs_cat.
//    Its store acks / HBM loads never pollute the poll path.
// Reuse of gates/flags at k+2 is safe: poll(h_{k+2}) success implies our
// service consumed gates[k+1] and (by order) gates[k].
__global__ __launch_bounds__(320, 1) void lstm_rec_k(
    const float* __restrict__ Whh_f, const float* __restrict__ Whh_b,
    const float* __restrict__ c0,
    const float* __restrict__ xg,      // [S][4096]
    ull* __restrict__ hbuf,            // [2 dir][2 slot][512]
    float* __restrict__ hs_cat)        // [S][1024]
{
  const int w = blockIdx.x;
  const int dir = w & 1;
  const int wid = w >> 1;              // 0..63
  const int t = threadIdx.x;           // 0..319

  __shared__ __align__(16) float h_lds[2][544];   // parity x (8 chunks * 68)
  __shared__ float gates_lds[2][32];              // parity x 32 row-sums
  __shared__ int   flags[2][4];                   // parity x compute-wave

  ull* hb = hbuf + dir * 1024;

  if (t < 8) flags[t >> 2][t & 3] = 0;
  __syncthreads();

  if (t < 256) {
    // ================= compute waves =================
    const int rr  = t >> 3;            // row 0..31
    const int seg = t & 7;             // 64-wide segment
    const int g   = rr & 3;            // gate
    const int unit = wid * 8 + (rr >> 2);
    const int grow = g * 512 + unit;
    const int wv  = t >> 6;            // compute wave 0..3

    const float* Whh = dir ? Whh_b : Whh_f;
    float wreg[64];
    {
      const float* srcW = Whh + (size_t)grow * 512 + seg * 64;
      #pragma unroll
      for (int j = 0; j < 16; ++j) {
        float4 v = *(const float4*)(srcW + j * 4);
        wreg[4 * j + 0] = v.x; wreg[4 * j + 1] = v.y;
        wreg[4 * j + 2] = v.z; wreg[4 * j + 3] = v.w;
      }
    }

    const int e0 = t * 2;              // entries {e0, e0+1}
    const int chunk = e0 >> 6, pos = e0 & 63;

    for (int k = 0; k < S; ++k) {
      const int par = k & 1;
      const unsigned want = (unsigned)(k + 1);
      ull* src = hb + par * 512 + e0;
      uint4v v;
      for (;;) {
        asm volatile("global_load_dwordx4 %0, %1, off sc0 sc1"
                     : "=v"(v) : "v"(src) : "memory");
        asm volatile("s_waitcnt vmcnt(0)" ::: "memory");   // exact: only poll in flight
        if (v.y == want && v.w == want) break;
        __builtin_amdgcn_s_sleep(1);
      }
      float* dst = &h_lds[par][chunk * 68 + pos];
      dst[0] = __uint_as_float(v.x);
      dst[1] = __uint_as_float(v.z);
      __syncthreads();

      const float4* h4 = (const float4*)(&h_lds[par][0] + seg * 68);
      float p0 = 0.f, p1 = 0.f, p2 = 0.f, p3 = 0.f;
      #pragma unroll
      for (int j = 0; j < 16; ++j) {
        float4 hv = h4[j];
        p0 = fmaf(wreg[4 * j + 0], hv.x, p0);
        p1 = fmaf(wreg[4 * j + 1], hv.y, p1);
        p2 = fmaf(wreg[4 * j + 2], hv.z, p2);
        p3 = fmaf(wreg[4 * j + 3], hv.w, p3);
      }
      float p = (p0 + p1) + (p2 + p3);
      p += __shfl_xor(p, 1);
      p += __shfl_xor(p, 2);
      p += __shfl_xor(p, 4);
      if (seg == 0) gates_lds[par][rr] = p;
      asm volatile("s_waitcnt lgkmcnt(0)" ::: "memory");   // gates visible before flag
      if ((t & 63) == 0) flags[par][wv] = k + 1;
    }
  } else {
    // ================= service wave =================
    const int r = t - 256;             // 0..63 (r<32 active)
    const int g = r & 3;
    const int unit = wid * 8 + (r >> 2);
    const int grow = g * 512 + unit;
    const bool act = (r < 32);

    float c_reg = 0.0f;
    if (act && g == 0) c_reg = c0[dir * 512 + unit];

    float xg_a = 0.0f, xg_b = 0.0f;
    if (act) {
      int r0 = dir ? (S - 1) : 0;
      int r1 = dir ? (S - 2) : 1;
      xg_a = xg[(size_t)r0 * 4096 + dir * 2048 + grow];
      xg_b = xg[(size_t)r1 * 4096 + dir * 2048 + grow];
    }

    for (int k = 0; k < S; ++k) {
      const int par = k & 1;
      float xgv = (k & 1) ? xg_b : xg_a;
      if (act && k + 2 < S) {          // 2-step xg pipeline (off poll path)
        int rowk = dir ? (S - 3 - k) : (k + 2);
        float nv = xg[(size_t)rowk * 4096 + dir * 2048 + grow];
        if (k & 1) xg_b = nv; else xg_a = nv;
      }
      __syncthreads();                 // matches compute waves' barrier

      const int want = k + 1;
      volatile int* fl = &flags[par][0];
      while (fl[0] != want || fl[1] != want || fl[2] != want || fl[3] != want) {}
      asm volatile("" ::: "memory");   // no hoisting of gates read above spin

      float gs = act ? (gates_lds[par][r] + xgv) : 0.0f;
      float b_ = __shfl_xor(gs, 1);    // gate g^1
      float c_ = __shfl_xor(gs, 2);    // gate g^2
      float d_ = __shfl_xor(b_, 2);    // gate g^3
      if (act && g == 0) {
        float iv = fsig(gs), fv = fsig(b_), ov = fsig(d_);
        float gv = ftanh(c_);
        c_reg = fv * c_reg + iv * gv;
        float hv = ov * ftanh(c_reg);
        ull pk = ((ull)(unsigned)(k + 2) << 32) | (ull)__float_as_uint(hv);
        __hip_atomic_store(&hb[((k + 1) & 1) * 512 + unit], pk,
                           __ATOMIC_RELAXED, __HIP_MEMORY_SCOPE_AGENT);
        int orig = dir ? (S - 1 - k) : k;
        hs_cat[(size_t)orig * 1024 + dir * 512 + unit] = hv;
      }
    }
  }
}

// ---------------- feats[t][j] = hs_cat[t] . Wout[j] + bout[j] ----------------
__global__ __launch_bounds__(64) void feats_k(
    const float* __restrict__ hs_cat, const float* __restrict__ Wout,
    const float* __restrict__ bout, float* __restrict__ feats)
{
  int tpos = blockIdx.x;
  int l = threadIdx.x;
  int j = l & 15, q = l >> 4;
  const float* h = hs_cat + (size_t)tpos * 1024 + q * 256;
  const float* wv = Wout + (size_t)j * 1024 + q * 256;
  float s = 0.f;
  #pragma unroll 8
  for (int i = 0; i < 256; i += 4) {
    float4 hv = *(const float4*)(h + i);
    float4 ww = *(const float4*)(wv + i);
    s = fmaf(hv.x, ww.x, s); s = fmaf(hv.y, ww.y, s);
    s = fmaf(hv.z, ww.z, s); s = fmaf(hv.w, ww.w, s);
  }
  s += __shfl_xor(s, 16);
  s += __shfl_xor(s, 32);
  if (q == 0) feats[tpos * 16 + j] = s + bout[j];
}

// ---------------- Viterbi: single wave, LDS-chunked feats, 4-bit backpointers ----------------
__global__ __launch_bounds__(64, 1) void viterbi_k(
    const float* __restrict__ feats, const float* __restrict__ trans,
    float* __restrict__ out)
{
  __shared__ __align__(16) float fch[2][256 * 16];  // 2 x 16KB double-buffer
  __shared__ unsigned char bp4[S * 8];              // 16KB packed nibbles
  __shared__ float v_lds[2][16];                    // double-buffered by step parity

  const int l = threadIdx.x;
  const int next = l & 15, q = l >> 4;

  float tr0 = trans[next * 16 + q * 4 + 0];
  float tr1 = trans[next * 16 + q * 4 + 1];
  float tr2 = trans[next * 16 + q * 4 + 2];
  float tr3 = trans[next * 16 + q * 4 + 3];

  if (l < 16) v_lds[0][l] = (l == 0) ? 0.0f : NEGV;   // START = 0

  const float4* f4 = (const float4*)feats;
  float4 buf[16];
  #pragma unroll
  for (int i = 0; i < 16; ++i) buf[i] = f4[i * 64 + l];
  #pragma unroll
  for (int i = 0; i < 16; ++i) ((float4*)fch[0])[i * 64 + l] = buf[i];
  __syncthreads();

  for (int c = 0; c < 8; ++c) {
    if (c < 7) {
      #pragma unroll
      for (int i = 0; i < 16; ++i) buf[i] = f4[(c + 1) * 1024 + i * 64 + l];
    }
    const float* fc = fch[c & 1];
    for (int tt = 0; tt < 256; ++tt) {
      int t = c * 256 + tt;
      int pb = t & 1;
      const float* vin = v_lds[pb];
      float m = vin[q * 4 + 0] + tr0; int mi = q * 4;
      float s1 = vin[q * 4 + 1] + tr1; if (s1 > m) { m = s1; mi = q * 4 + 1; }
      float s2 = vin[q * 4 + 2] + tr2; if (s2 > m) { m = s2; mi = q * 4 + 2; }
      float s3 = vin[q * 4 + 3] + tr3; if (s3 > m) { m = s3; mi = q * 4 + 3; }
      #pragma unroll
      for (int mask = 16; mask <= 32; mask <<= 1) {
        float om = __shfl_xor(m, mask);
        int omi = __shfl_xor(mi, mask);
        if (om > m || (om == m && omi < mi)) { m = om; mi = omi; }
      }
      int pmi = __shfl_xor(mi, 1);
      if (q == 0) {
        v_lds[pb ^ 1][next] = m + fc[tt * 16 + next];
        if ((next & 1) == 0)
          bp4[t * 8 + (next >> 1)] = (unsigned char)((mi & 15) | ((pmi & 15) << 4));
      }
      __syncthreads();   // one barrier per step (double-buffered v)
    }
    if (c < 7) {
      #pragma unroll
      for (int i = 0; i < 16; ++i) ((float4*)fch[(c + 1) & 1])[i * 64 + l] = buf[i];
      __syncthreads();
    }
  }

  // after t = S-1 (odd), final v is in v_lds[0]
  float term = (l < 16) ? (v_lds[0][l] + trans[1 * 16 + l]) : -3.0e38f;
  int ti = (l < 16) ? l : 0;
  #pragma unroll
  for (int mask = 1; mask <= 32; mask <<= 1) {
    float om = __shfl_xor(term, mask);
    int omi = __shfl_xor(ti, mask);
    if (om > term || (om == term && omi < ti)) { term = om; ti = omi; }
  }
  if (l == 0) {
    out[0] = term;
    int tag = ti;
    out[1 + (S - 1)] = (float)tag;
    for (int t = S - 1; t >= 1; --t) {
      tag = (bp4[t * 8 + (tag >> 1)] >> ((tag & 1) * 4)) & 15;
      out[t] = (float)tag;   // out[1 + (t-1)]
    }
  }
}

extern "C" void kernel_launch(void* const* d_in, const int* in_sizes, int n_in,
                              void* d_out, int out_size, void* d_ws, size_t ws_size,
                              hipStream_t stream) {
  const int*   sent  = (const int*)d_in[0];
  const float* emb   = (const float*)d_in[1];
  const float* Wih_f = (const float*)d_in[2];
  const float* Whh_f = (const float*)d_in[3];
  const float* bih_f = (const float*)d_in[4];
  const float* bhh_f = (const float*)d_in[5];
  const float* Wih_b = (const float*)d_in[6];
  const float* Whh_b = (const float*)d_in[7];
  const float* bih_b = (const float*)d_in[8];
  const float* bhh_b = (const float*)d_in[9];
  const float* h0    = (const float*)d_in[10];
  const float* c0    = (const float*)d_in[11];
  const float* Wout  = (const float*)d_in[12];
  const float* bout  = (const float*)d_in[13];
  const float* trans = (const float*)d_in[14];
  float* out = (float*)d_out;

  // workspace layout
  char* ws = (char*)d_ws;
  float* xg     = (float*)(ws);                         // 2048*4096*4 = 32 MiB
  float* hs_cat = (float*)(ws + 33554432);              // 2048*1024*4 = 8 MiB
  float* feats  = (float*)(ws + 41943040);              // 2048*16*4 = 128 KiB
  ull*   hbuf   = (ull*)  (ws + 42074112);              // 2*2*512*8 = 16 KiB

  init_h_k<<<2, 512, 0, stream>>>(h0, hbuf);
  gemm_xg_k<<<dim3(64, 32), 256, 0, stream>>>(sent, emb, Wih_f, Wih_b,
                                              bih_f, bhh_f, bih_b, bhh_b, xg);
  lstm_rec_k<<<128, 320, 0, stream>>>(Whh_f, Whh_b, c0, xg, hbuf, hs_cat);
  feats_k<<<2048, 64, 0, stream>>>(hs_cat, Wout, bout, feats);
  viterbi_k<<<1, 64, 0, stream>>>(feats, trans, out);
}

// Round 7
// 5108.174 us; speedup vs baseline: 1.0663x; 1.0663x over previous
//
#include <hip/hip_runtime.h>
#include <hip/hip_bf16.h>

#define S 2048
#define NEGV -10000.0f

typedef unsigned long long ull;
typedef unsigned int uint4v __attribute__((ext_vector_type(4)));

__device__ __forceinline__ float fsig(float x) {
  return 1.0f / (1.0f + __expf(-x));
}
__device__ __forceinline__ float ftanh(float x) {
  float a = fabsf(x);
  float e = __expf(-2.0f * a);
  float r = (1.0f - e) / (1.0f + e);
  return copysignf(r, x);
}

// ---------------- clear xg-tile readiness flags (every call; no poison reliance) ----
__global__ void clear_flags_k(int* __restrict__ flags) {
  flags[blockIdx.x * 256 + threadIdx.x] = 0;
}

// ---------------- init: seed h0 with stamp 1, invalidate other slot ----------------
__global__ void init_h_k(const float* __restrict__ h0, ull* __restrict__ hbuf) {
  int dir = blockIdx.x;          // 0,1
  int u = threadIdx.x;           // 0..511
  ull pk = (1ULL << 32) | (ull)__float_as_uint(h0[dir * 512 + u]);
  __hip_atomic_store(&hbuf[dir * 1024 + u], pk, __ATOMIC_RELAXED, __HIP_MEMORY_SCOPE_AGENT);
  __hip_atomic_store(&hbuf[dir * 1024 + 512 + u], 0ULL, __ATOMIC_RELAXED, __HIP_MEMORY_SCOPE_AGENT);
}

// ---------------- FUSED kernel: blocks 0..127 = LSTM recurrence, 128..2175 = xg GEMM ----
// GEMM role: 64x64 tile of xg[m][n] = emb[sent[m]].Wrow(n)+bias; tiles ordered so the
// chain-head rows (m=0 fwd, m=2047 bwd) complete first; publishes via agent write-through
// atomic stores + vmcnt(0) + flags[by][bx]=1 (relaxed agent).
// LSTM role: R5 structure (proven 1.51us/step): 128 WGs x 256thr, dir=wg&1, wid=wg>>1
// owns units wid*8..+7; 16B sc0sc1 stamp-fused polls + sleep backoff; xg now staged
// 32 steps at a time into LDS (double-buffered) gated by the tile flags.
__global__ __launch_bounds__(256) void fused_k(
    const int* __restrict__ sent, const float* __restrict__ emb,
    const float* __restrict__ Wih_f, const float* __restrict__ Wih_b,
    const float* __restrict__ bih_f, const float* __restrict__ bhh_f,
    const float* __restrict__ bih_b, const float* __restrict__ bhh_b,
    const float* __restrict__ Whh_f, const float* __restrict__ Whh_b,
    const float* __restrict__ c0,
    float* __restrict__ xg,            // [S][4096]
    ull* __restrict__ hbuf,            // [2 dir][2 slot][512]
    float* __restrict__ hs_cat,        // [S][1024]
    int* __restrict__ flags)           // [32 by][64 bx]
{
  __shared__ __align__(16) float smem[4544];   // union: gemm 4544f / lstm 3136f
  const int t = threadIdx.x;

  if (blockIdx.x >= 128) {
    // ================= GEMM role =================
    const int gid = blockIdx.x - 128;          // 0..2047
    const int byo = gid >> 6, bxo = gid & 63;
    const int by = (byo & 1) ? (31 - (byo >> 1)) : (byo >> 1);   // 0,31,1,30,...
    const int bx = (bxo & 1) ? (32 + (bxo >> 1)) : (bxo >> 1);   // fwd/bwd interleave
    const int n0 = bx * 64, m0 = by * 64;

    float* Asm = smem;                 // [64][36]
    float* Bsm = smem + 2304;          // [32][68]
    int*   sidx = (int*)(smem + 4480); // [64]

    const float* W = (n0 < 2048) ? (Wih_f + (size_t)n0 * 1024)
                                 : (Wih_b + (size_t)(n0 - 2048) * 1024);
    if (t < 64) sidx[t] = sent[m0 + t];
    __syncthreads();

    const int tm = t >> 4, tn = t & 15;
    const int lr = t >> 2, lkq = t & 3;
    float acc[4][4] = {};

    for (int k0 = 0; k0 < 1024; k0 += 32) {
      const float* ap = emb + (size_t)sidx[lr] * 1024 + k0 + lkq * 8;
      float4 a0 = *(const float4*)ap;
      float4 a1 = *(const float4*)(ap + 4);
      const float* bp = W + (size_t)lr * 1024 + k0 + lkq * 8;
      float4 b0 = *(const float4*)bp;
      float4 b1 = *(const float4*)(bp + 4);
      __syncthreads();
      *(float4*)&Asm[lr * 36 + lkq * 8]     = a0;
      *(float4*)&Asm[lr * 36 + lkq * 8 + 4] = a1;
      {
        const float* bb0 = (const float*)&b0;
        const float* bb1 = (const float*)&b1;
        #pragma unroll
        for (int j = 0; j < 4; ++j) Bsm[(lkq * 8 + j) * 68 + lr] = bb0[j];
        #pragma unroll
        for (int j = 0; j < 4; ++j) Bsm[(lkq * 8 + 4 + j) * 68 + lr] = bb1[j];
      }
      __syncthreads();
      #pragma unroll
      for (int kk = 0; kk < 32; ++kk) {
        float a0_ = Asm[(tm * 4 + 0) * 36 + kk];
        float a1_ = Asm[(tm * 4 + 1) * 36 + kk];
        float a2_ = Asm[(tm * 4 + 2) * 36 + kk];
        float a3_ = Asm[(tm * 4 + 3) * 36 + kk];
        float4 bv = *(const float4*)&Bsm[kk * 68 + tn * 4];
        acc[0][0] = fmaf(a0_, bv.x, acc[0][0]); acc[0][1] = fmaf(a0_, bv.y, acc[0][1]);
        acc[0][2] = fmaf(a0_, bv.z, acc[0][2]); acc[0][3] = fmaf(a0_, bv.w, acc[0][3]);
        acc[1][0] = fmaf(a1_, bv.x, acc[1][0]); acc[1][1] = fmaf(a1_, bv.y, acc[1][1]);
        acc[1][2] = fmaf(a1_, bv.z, acc[1][2]); acc[1][3] = fmaf(a1_, bv.w, acc[1][3]);
        acc[2][0] = fmaf(a2_, bv.x, acc[2][0]); acc[2][1] = fmaf(a2_, bv.y, acc[2][1]);
        acc[2][2] = fmaf(a2_, bv.z, acc[2][2]); acc[2][3] = fmaf(a2_, bv.w, acc[2][3]);
        acc[3][0] = fmaf(a3_, bv.x, acc[3][0]); acc[3][1] = fmaf(a3_, bv.y, acc[3][1]);
        acc[3][2] = fmaf(a3_, bv.z, acc[3][2]); acc[3][3] = fmaf(a3_, bv.w, acc[3][3]);
      }
    }

    const float* bi = (n0 < 2048) ? bih_f : bih_b;
    const float* bh = (n0 < 2048) ? bhh_f : bhh_b;
    const int nb = (n0 < 2048) ? n0 : (n0 - 2048);
    #pragma unroll
    for (int i = 0; i < 4; ++i) {
      int m = m0 + tm * 4 + i;
      #pragma unroll
      for (int j = 0; j < 4; ++j) {
        int nn = tn * 4 + j;
        float bias = bi[nb + nn] + bh[nb + nn];
        // agent write-through so consumers' coherent loads see it at the LLC
        __hip_atomic_store(&xg[(size_t)m * 4096 + n0 + nn], acc[i][j] + bias,
                           __ATOMIC_RELAXED, __HIP_MEMORY_SCOPE_AGENT);
      }
    }
    asm volatile("s_waitcnt vmcnt(0)" ::: "memory");   // stores acked at coherence pt
    __syncthreads();
    if (t == 0)
      __hip_atomic_store(&flags[by * 64 + bx], 1, __ATOMIC_RELAXED, __HIP_MEMORY_SCOPE_AGENT);
    return;
  }

  // ================= LSTM role (R5 structure + chunked xg) =================
  const int w = blockIdx.x;
  const int dir = w & 1;
  const int wid = w >> 1;              // 0..63
  const int rr = t >> 3;               // row-in-wg 0..31
  const int seg = t & 7;               // 0..7
  const int g  = rr & 3;               // gate 0..3 (i,f,g,o)
  const int ul = rr >> 2;              // local unit 0..7
  const int unit = wid * 8 + ul;       // 0..511
  const int grow = g * 512 + unit;     // global Whh row

  float (*h_lds)[544] = (float(*)[544])smem;         // [2][544]
  float (*xgbuf)[1024] = (float(*)[1024])(smem + 1088); // [2][32*32]

  const float* Whh = dir ? Whh_b : Whh_f;
  float wreg[64];
  {
    const float* src = Whh + (size_t)grow * 512 + seg * 64;
    #pragma unroll
    for (int j = 0; j < 16; ++j) {
      float4 v = *(const float4*)(src + j * 4);
      wreg[4 * j + 0] = v.x; wreg[4 * j + 1] = v.y;
      wreg[4 * j + 2] = v.z; wreg[4 * j + 3] = v.w;
    }
  }

  ull* hb = hbuf + dir * 1024;
  float c_reg = c0[dir * 512 + unit];  // meaningful on g==0 lanes

  const int u0 = t * 2;
  const int wchunk = u0 >> 6, wpos = u0 & 63;

  // xg chunk loader mapping: thread t loads step s=t>>3 of the chunk,
  // float4 index (t&7) = gate g2 (x2) + half -> cols g2*512 + wid*8 + half*4
  const int ls   = t >> 3;             // 0..31 step-in-chunk
  const int g2   = (t & 7) >> 1;       // gate 0..3
  const int half = t & 1;              // 0/1
  const int bxf  = dir * 32 + g2 * 8 + (wid >> 3);   // flag col for my gate
  const int xgoff = ls * 32 + (t & 7) * 4;           // LDS float4 slot
  const int xgcons = g * 8 + ul;                     // consumption index

  for (int k = 0; k < S; ++k) {
    const int par = k & 1;
    const int cpar = (k >> 5) & 1;
    uint4v xv;
    const bool chunk = ((k & 31) == 0);
    if (chunk) {
      const int by = dir ? ((S - 1 - k) >> 6) : (k >> 6);
      while (__hip_atomic_load(&flags[by * 64 + bxf], __ATOMIC_RELAXED,
                               __HIP_MEMORY_SCOPE_AGENT) != 1)
        __builtin_amdgcn_s_sleep(8);
      const int row = dir ? (S - 1 - (k + ls)) : (k + ls);
      const float* xsrc = xg + (size_t)row * 4096 + dir * 2048 + g2 * 512 + wid * 8 + half * 4;
      asm volatile("global_load_dwordx4 %0, %1, off sc0 sc1"
                   : "=v"(xv) : "v"(xsrc) : "memory");
    }
    // poll h_k: stamp k+1 in slot k&1; 16B coherent load, sleep backoff
    {
      ull* src = hb + par * 512 + u0;
      const unsigned want = (unsigned)(k + 1);
      uint4v v;
      asm volatile("global_load_dwordx4 %0, %1, off sc0 sc1"
                   : "=v"(v) : "v"(src) : "memory");
      asm volatile("s_waitcnt vmcnt(0)" ::: "memory");
      while (v.y != want || v.w != want) {
        __builtin_amdgcn_s_sleep(1);
        asm volatile("global_load_dwordx4 %0, %1, off sc0 sc1"
                     : "=v"(v) : "v"(src) : "memory");
        asm volatile("s_waitcnt vmcnt(0)" ::: "memory");
      }
      if (chunk) *((uint4v*)&xgbuf[cpar][xgoff]) = xv;   // xv drained by vmcnt above
      float* dst = &h_lds[par][wchunk * 68 + wpos];
      dst[0] = __uint_as_float(v.x);
      dst[1] = __uint_as_float(v.z);
    }
    __syncthreads();

    // 64-wide partial dot of row `grow`
    const float* hl = &h_lds[par][0];
    float p0 = 0.f, p1 = 0.f, p2 = 0.f, p3 = 0.f;
    const float4* h4 = (const float4*)(hl + seg * 68);
    #pragma unroll
    for (int j = 0; j < 16; ++j) {
      float4 hv = h4[j];
      p0 = fmaf(wreg[4 * j + 0], hv.x, p0);
      p1 = fmaf(wreg[4 * j + 1], hv.y, p1);
      p2 = fmaf(wreg[4 * j + 2], hv.z, p2);
      p3 = fmaf(wreg[4 * j + 3], hv.w, p3);
    }
    float xgv = (seg == 0) ? xgbuf[cpar][(k & 31) * 32 + xgcons] : 0.0f;
    float p = (p0 + p1) + (p2 + p3) + xgv;
    p += __shfl_xor(p, 1);
    p += __shfl_xor(p, 2);
    p += __shfl_xor(p, 4);
    float gb_ = __shfl_xor(p, 8);      // gate g^1
    float gc_ = __shfl_xor(p, 16);     // gate g^2
    float gd_ = __shfl_xor(gb_, 16);   // gate g^3
    if (g == 0) {
      float iv = fsig(p), fv = fsig(gb_), ov = fsig(gd_);
      float gv = ftanh(gc_);
      c_reg = fv * c_reg + iv * gv;
      float hv = ov * ftanh(c_reg);
      if (seg == 0) {
        ull pk = ((ull)(unsigned)(k + 2) << 32) | (ull)__float_as_uint(hv);
        __hip_atomic_store(&hb[((k + 1) & 1) * 512 + unit], pk,
                           __ATOMIC_RELAXED, __HIP_MEMORY_SCOPE_AGENT);
        int orig = dir ? (S - 1 - k) : k;
        hs_cat[(size_t)orig * 1024 + dir * 512 + unit] = hv;
      }
    }
  }
}

// ---------------- feats[t][j] = hs_cat[t] . Wout[j] + bout[j] ----------------
__global__ __launch_bounds__(64) void feats_k(
    const float* __restrict__ hs_cat, const float* __restrict__ Wout,
    const float* __restrict__ bout, float* __restrict__ feats)
{
  int tpos = blockIdx.x;
  int l = threadIdx.x;
  int j = l & 15, q = l >> 4;
  const float* h = hs_cat + (size_t)tpos * 1024 + q * 256;
  const float* wv = Wout + (size_t)j * 1024 + q * 256;
  float s = 0.f;
  #pragma unroll 8
  for (int i = 0; i < 256; i += 4) {
    float4 hv = *(const float4*)(h + i);
    float4 ww = *(const float4*)(wv + i);
    s = fmaf(hv.x, ww.x, s); s = fmaf(hv.y, ww.y, s);
    s = fmaf(hv.z, ww.z, s); s = fmaf(hv.w, ww.w, s);
  }
  s += __shfl_xor(s, 16);
  s += __shfl_xor(s, 32);
  if (q == 0) feats[tpos * 16 + j] = s + bout[j];
}

// ---------------- Viterbi: single wave, LDS-chunked feats, 4-bit backpointers ----------------
__global__ __launch_bounds__(64, 1) void viterbi_k(
    const float* __restrict__ feats, const float* __restrict__ trans,
    float* __restrict__ out)
{
  __shared__ __align__(16) float fch[2][256 * 16];  // 2 x 16KB double-buffer
  __shared__ unsigned char bp4[S * 8];              // 16KB packed nibbles
  __shared__ float v_lds[2][16];                    // double-buffered by step parity

  const int l = threadIdx.x;
  const int next = l & 15, q = l >> 4;

  float tr0 = trans[next * 16 + q * 4 + 0];
  float tr1 = trans[next * 16 + q * 4 + 1];
  float tr2 = trans[next * 16 + q * 4 + 2];
  float tr3 = trans[next * 16 + q * 4 + 3];

  if (l < 16) v_lds[0][l] = (l == 0) ? 0.0f : NEGV;   // START = 0

  const float4* f4 = (const float4*)feats;
  float4 buf[16];
  #pragma unroll
  for (int i = 0; i < 16; ++i) buf[i] = f4[i * 64 + l];
  #pragma unroll
  for (int i = 0; i < 16; ++i) ((float4*)fch[0])[i * 64 + l] = buf[i];
  __syncthreads();

  for (int c = 0; c < 8; ++c) {
    if (c < 7) {
      #pragma unroll
      for (int i = 0; i < 16; ++i) buf[i] = f4[(c + 1) * 1024 + i * 64 + l];
    }
    const float* fc = fch[c & 1];
    for (int tt = 0; tt < 256; ++tt) {
      int t = c * 256 + tt;
      int pb = t & 1;
      const float* vin = v_lds[pb];
      float m = vin[q * 4 + 0] + tr0; int mi = q * 4;
      float s1 = vin[q * 4 + 1] + tr1; if (s1 > m) { m = s1; mi = q * 4 + 1; }
      float s2 = vin[q * 4 + 2] + tr2; if (s2 > m) { m = s2; mi = q * 4 + 2; }
      float s3 = vin[q * 4 + 3] + tr3; if (s3 > m) { m = s3; mi = q * 4 + 3; }
      #pragma unroll
      for (int mask = 16; mask <= 32; mask <<= 1) {
        float om = __shfl_xor(m, mask);
        int omi = __shfl_xor(mi, mask);
        if (om > m || (om == m && omi < mi)) { m = om; mi = omi; }
      }
      int pmi = __shfl_xor(mi, 1);
      if (q == 0) {
        v_lds[pb ^ 1][next] = m + fc[tt * 16 + next];
        if ((next & 1) == 0)
          bp4[t * 8 + (next >> 1)] = (unsigned char)((mi & 15) | ((pmi & 15) << 4));
      }
      __syncthreads();   // one barrier per step (double-buffered v)
    }
    if (c < 7) {
      #pragma unroll
      for (int i = 0; i < 16; ++i) ((float4*)fch[(c + 1) & 1])[i * 64 + l] = buf[i];
      __syncthreads();
    }
  }

  // after t = S-1 (odd), final v is in v_lds[0]
  float term = (l < 16) ? (v_lds[0][l] + trans[1 * 16 + l]) : -3.0e38f;
  int ti = (l < 16) ? l : 0;
  #pragma unroll
  for (int mask = 1; mask <= 32; mask <<= 1) {
    float om = __shfl_xor(term, mask);
    int omi = __shfl_xor(ti, mask);
    if (om > term || (om == term && omi < ti)) { term = om; ti = omi; }
  }
  if (l == 0) {
    out[0] = term;
    int tag = ti;
    out[1 + (S - 1)] = (float)tag;
    for (int t = S - 1; t >= 1; --t) {
      tag = (bp4[t * 8 + (tag >> 1)] >> ((tag & 1) * 4)) & 15;
      out[t] = (float)tag;   // out[1 + (t-1)]
    }
  }
}

extern "C" void kernel_launch(void* const* d_in, const int* in_sizes, int n_in,
                              void* d_out, int out_size, void* d_ws, size_t ws_size,
                              hipStream_t stream) {
  const int*   sent  = (const int*)d_in[0];
  const float* emb   = (const float*)d_in[1];
  const float* Wih_f = (const float*)d_in[2];
  const float* Whh_f = (const float*)d_in[3];
  const float* bih_f = (const float*)d_in[4];
  const float* bhh_f = (const float*)d_in[5];
  const float* Wih_b = (const float*)d_in[6];
  const float* Whh_b = (const float*)d_in[7];
  const float* bih_b = (const float*)d_in[8];
  const float* bhh_b = (const float*)d_in[9];
  const float* h0    = (const float*)d_in[10];
  const float* c0    = (const float*)d_in[11];
  const float* Wout  = (const float*)d_in[12];
  const float* bout  = (const float*)d_in[13];
  const float* trans = (const float*)d_in[14];
  float* out = (float*)d_out;

  // workspace layout
  char* ws = (char*)d_ws;
  float* xg     = (float*)(ws);                         // 2048*4096*4 = 32 MiB
  float* hs_cat = (float*)(ws + 33554432);              // 2048*1024*4 = 8 MiB
  float* feats  = (float*)(ws + 41943040);              // 2048*16*4 = 128 KiB
  ull*   hbuf   = (ull*)  (ws + 42074112);              // 2*2*512*8 = 16 KiB
  int*   flags  = (int*)  (ws + 42090496);              // 32*64*4 = 8 KiB

  clear_flags_k<<<8, 256, 0, stream>>>(flags);
  init_h_k<<<2, 512, 0, stream>>>(h0, hbuf);
  fused_k<<<2176, 256, 0, stream>>>(sent, emb, Wih_f, Wih_b, bih_f, bhh_f,
                                    bih_b, bhh_b, Whh_f, Whh_b, c0,
                                    xg, hbuf, hs_cat, flags);
  feats_k<<<2048, 64, 0, stream>>>(hs_cat, Wout, bout, feats);
  viterbi_k<<<1, 64, 0, stream>>>(feats, trans, out);
}

// Round 8
// 3921.267 us; speedup vs baseline: 1.3891x; 1.3027x over previous
//
#include <hip/hip_runtime.h>
#include <hip/hip_bf16.h>

#define S 2048
#define NEGV -10000.0f

typedef unsigned long long ull;
typedef unsigned int uint4v __attribute__((ext_vector_type(4)));

__device__ __forceinline__ float fsig(float x) {
  return 1.0f / (1.0f + __expf(-x));
}
__device__ __forceinline__ float ftanh(float x) {
  float a = fabsf(x);
  float e = __expf(-2.0f * a);
  float r = (1.0f - e) / (1.0f + e);
  return copysignf(r, x);
}

// ---------------- clear xg-tile readiness flags (every call) ----------------
__global__ void clear_flags_k(int* __restrict__ flags) {
  flags[blockIdx.x * 256 + threadIdx.x] = 0;
}

// ---------------- init: seed h0 with stamp 1, invalidate other slot ----------------
__global__ void init_h_k(const float* __restrict__ h0, ull* __restrict__ hbuf) {
  int dir = blockIdx.x;          // 0,1
  int u = threadIdx.x;           // 0..511
  ull pk = (1ULL << 32) | (ull)__float_as_uint(h0[dir * 512 + u]);
  __hip_atomic_store(&hbuf[dir * 1024 + u], pk, __ATOMIC_RELAXED, __HIP_MEMORY_SCOPE_AGENT);
  __hip_atomic_store(&hbuf[dir * 1024 + 512 + u], 0ULL, __ATOMIC_RELAXED, __HIP_MEMORY_SCOPE_AGENT);
}

// ---------------- FUSED: blocks 0..127 LSTM (R5 structure), 128..255 persistent GEMM ----
// One block per CU (grid=256): no CU sharing between roles.
// GEMM worker b handles tiles rank T=b-128+128*i, i<16; rank->tile prioritizes both
// chain heads (by order 0,31,1,30,..; bx interleaves fwd/bwd halves). Publishes tile
// via agent write-through stores + vmcnt(0) + flags[by*64+bx]=1.
// LSTM: exact R5 chain; xg read via agent relaxed atomic loads (coherent vs concurrent
// producer); spins on its 4 gate-column flags only when prefetch crosses a 64-row block.
__global__ __launch_bounds__(256) void fused_k(
    const int* __restrict__ sent, const float* __restrict__ emb,
    const float* __restrict__ Wih_f, const float* __restrict__ Wih_b,
    const float* __restrict__ bih_f, const float* __restrict__ bhh_f,
    const float* __restrict__ bih_b, const float* __restrict__ bhh_b,
    const float* __restrict__ Whh_f, const float* __restrict__ Whh_b,
    const float* __restrict__ c0,
    float* __restrict__ xg,            // [S][4096]
    ull* __restrict__ hbuf,            // [2 dir][2 slot][512]
    float* __restrict__ hs_cat,        // [S][1024]
    int* __restrict__ flags)           // [32 by][64 bx]
{
  __shared__ __align__(16) float smem[4544];   // gemm: Asm|Bsm|sidx ; lstm: h_lds
  const int t = threadIdx.x;

  if (blockIdx.x >= 128) {
    // ================= persistent GEMM worker =================
    float* Asm = smem;                 // [64][36]
    float* Bsm = smem + 2304;          // [32][68]
    int*   sidx = (int*)(smem + 4480); // [64]
    const int tm = t >> 4, tn = t & 15;
    const int lr = t >> 2, lkq = t & 3;

    for (int i = 0; i < 16; ++i) {
      const int T = (blockIdx.x - 128) + 128 * i;   // priority rank
      const int byo = T >> 6, bxo = T & 63;
      const int by = (byo & 1) ? (31 - (byo >> 1)) : (byo >> 1);
      const int bx = (bxo & 1) ? (32 + (bxo >> 1)) : (bxo >> 1);
      const int n0 = bx * 64, m0 = by * 64;

      const float* W = (n0 < 2048) ? (Wih_f + (size_t)n0 * 1024)
                                   : (Wih_b + (size_t)(n0 - 2048) * 1024);
      __syncthreads();                 // prev tile fully consumed LDS
      if (t < 64) sidx[t] = sent[m0 + t];
      __syncthreads();

      float acc[4][4] = {};
      for (int k0 = 0; k0 < 1024; k0 += 32) {
        const float* ap = emb + (size_t)sidx[lr] * 1024 + k0 + lkq * 8;
        float4 a0 = *(const float4*)ap;
        float4 a1 = *(const float4*)(ap + 4);
        const float* bp = W + (size_t)lr * 1024 + k0 + lkq * 8;
        float4 b0 = *(const float4*)bp;
        float4 b1 = *(const float4*)(bp + 4);
        __syncthreads();
        *(float4*)&Asm[lr * 36 + lkq * 8]     = a0;
        *(float4*)&Asm[lr * 36 + lkq * 8 + 4] = a1;
        {
          const float* bb0 = (const float*)&b0;
          const float* bb1 = (const float*)&b1;
          #pragma unroll
          for (int j = 0; j < 4; ++j) Bsm[(lkq * 8 + j) * 68 + lr] = bb0[j];
          #pragma unroll
          for (int j = 0; j < 4; ++j) Bsm[(lkq * 8 + 4 + j) * 68 + lr] = bb1[j];
        }
        __syncthreads();
        #pragma unroll
        for (int kk = 0; kk < 32; ++kk) {
          float a0_ = Asm[(tm * 4 + 0) * 36 + kk];
          float a1_ = Asm[(tm * 4 + 1) * 36 + kk];
          float a2_ = Asm[(tm * 4 + 2) * 36 + kk];
          float a3_ = Asm[(tm * 4 + 3) * 36 + kk];
          float4 bv = *(const float4*)&Bsm[kk * 68 + tn * 4];
          acc[0][0] = fmaf(a0_, bv.x, acc[0][0]); acc[0][1] = fmaf(a0_, bv.y, acc[0][1]);
          acc[0][2] = fmaf(a0_, bv.z, acc[0][2]); acc[0][3] = fmaf(a0_, bv.w, acc[0][3]);
          acc[1][0] = fmaf(a1_, bv.x, acc[1][0]); acc[1][1] = fmaf(a1_, bv.y, acc[1][1]);
          acc[1][2] = fmaf(a1_, bv.z, acc[1][2]); acc[1][3] = fmaf(a1_, bv.w, acc[1][3]);
          acc[2][0] = fmaf(a2_, bv.x, acc[2][0]); acc[2][1] = fmaf(a2_, bv.y, acc[2][1]);
          acc[2][2] = fmaf(a2_, bv.z, acc[2][2]); acc[2][3] = fmaf(a2_, bv.w, acc[2][3]);
          acc[3][0] = fmaf(a3_, bv.x, acc[3][0]); acc[3][1] = fmaf(a3_, bv.y, acc[3][1]);
          acc[3][2] = fmaf(a3_, bv.z, acc[3][2]); acc[3][3] = fmaf(a3_, bv.w, acc[3][3]);
        }
      }

      const float* bi = (n0 < 2048) ? bih_f : bih_b;
      const float* bh = (n0 < 2048) ? bhh_f : bhh_b;
      const int nb = (n0 < 2048) ? n0 : (n0 - 2048);
      #pragma unroll
      for (int ii = 0; ii < 4; ++ii) {
        int m = m0 + tm * 4 + ii;
        #pragma unroll
        for (int j = 0; j < 4; ++j) {
          int nn = tn * 4 + j;
          float bias = bi[nb + nn] + bh[nb + nn];
          __hip_atomic_store(&xg[(size_t)m * 4096 + n0 + nn], acc[ii][j] + bias,
                             __ATOMIC_RELAXED, __HIP_MEMORY_SCOPE_AGENT);
        }
      }
      asm volatile("s_waitcnt vmcnt(0)" ::: "memory");
      __syncthreads();
      if (t == 0)
        __hip_atomic_store(&flags[by * 64 + bx], 1, __ATOMIC_RELAXED, __HIP_MEMORY_SCOPE_AGENT);
    }
    return;
  }

  // ================= LSTM role (exact R5 chain + flag-gated xg) =================
  const int w = blockIdx.x;
  const int dir = w & 1;
  const int wid = w >> 1;              // 0..63
  const int rr = t >> 3;               // row-in-wg 0..31
  const int seg = t & 7;               // 0..7
  const int g  = rr & 3;               // gate 0..3 (i,f,g,o)
  const int ul = rr >> 2;              // local unit 0..7
  const int unit = wid * 8 + ul;       // 0..511
  const int grow = g * 512 + unit;     // global Whh row
  const int bxf  = dir * 32 + g * 8 + (wid >> 3);   // flag column for this row's xg

  float (*h_lds)[544] = (float(*)[544])smem;        // [2][544]

  const float* Whh = dir ? Whh_b : Whh_f;
  float wreg[64];
  {
    const float* src = Whh + (size_t)grow * 512 + seg * 64;
    #pragma unroll
    for (int j = 0; j < 16; ++j) {
      float4 v = *(const float4*)(src + j * 4);
      wreg[4 * j + 0] = v.x; wreg[4 * j + 1] = v.y;
      wreg[4 * j + 2] = v.z; wreg[4 * j + 3] = v.w;
    }
  }

  ull* hb = hbuf + dir * 1024;
  float c_reg = c0[dir * 512 + unit];  // meaningful on g==0 lanes

  const int u0 = t * 2;
  const int wchunk = u0 >> 6, wpos = u0 & 63;

  // initial xg: rows {0,1} (fwd) / {S-1,S-2} (bwd) live in by 0 / 31 — gate then load
  float xg_a = 0.0f, xg_b = 0.0f;
  if (seg == 0) {
    int by0 = dir ? 31 : 0;
    while (__hip_atomic_load(&flags[by0 * 64 + bxf], __ATOMIC_RELAXED,
                             __HIP_MEMORY_SCOPE_AGENT) != 1)
      __builtin_amdgcn_s_sleep(8);
    int r0 = dir ? (S - 1) : 0;
    int r1 = dir ? (S - 2) : 1;
    xg_a = __hip_atomic_load(&xg[(size_t)r0 * 4096 + dir * 2048 + grow],
                             __ATOMIC_RELAXED, __HIP_MEMORY_SCOPE_AGENT);
    xg_b = __hip_atomic_load(&xg[(size_t)r1 * 4096 + dir * 2048 + grow],
                             __ATOMIC_RELAXED, __HIP_MEMORY_SCOPE_AGENT);
  }

  #define LSTM_STEP(K, XG_REG)                                                  \
  {                                                                             \
    const int k = (K);                                                          \
    float xgv = XG_REG;                                                         \
    if (seg == 0 && k + 2 < S) {       /* prefetch row k+2 into same reg */     \
      int rowk = dir ? (S - 3 - k) : (k + 2);                                   \
      if ((rowk & 63) == (dir ? 63 : 0)) {   /* entering new 64-row block */    \
        int byn = rowk >> 6;                                                    \
        while (__hip_atomic_load(&flags[byn * 64 + bxf], __ATOMIC_RELAXED,      \
                                 __HIP_MEMORY_SCOPE_AGENT) != 1)                \
          __builtin_amdgcn_s_sleep(8);                                          \
      }                                                                         \
      XG_REG = __hip_atomic_load(&xg[(size_t)rowk * 4096 + dir * 2048 + grow],  \
                                 __ATOMIC_RELAXED, __HIP_MEMORY_SCOPE_AGENT);   \
    }                                                                           \
    /* poll h_k: stamp k+1 in slot k&1; 16B coherent load, sleep backoff */     \
    {                                                                           \
      ull* src = hb + (k & 1) * 512 + u0;                                       \
      const unsigned want = (unsigned)(k + 1);                                  \
      uint4v v;                                                                 \
      asm volatile("global_load_dwordx4 %0, %1, off sc0 sc1"                    \
                   : "=v"(v) : "v"(src) : "memory");                            \
      asm volatile("s_waitcnt vmcnt(0)" ::: "memory");                          \
      while (v.y != want || v.w != want) {                                      \
        __builtin_amdgcn_s_sleep(1);                                            \
        asm volatile("global_load_dwordx4 %0, %1, off sc0 sc1"                  \
                     : "=v"(v) : "v"(src) : "memory");                          \
        asm volatile("s_waitcnt vmcnt(0)" ::: "memory");                        \
      }                                                                         \
      float* dst = &h_lds[k & 1][wchunk * 68 + wpos];                           \
      dst[0] = __uint_as_float(v.x);                                            \
      dst[1] = __uint_as_float(v.z);                                            \
    }                                                                           \
    __syncthreads();                                                            \
    /* 64-wide partial dot of row `grow` */                                     \
    const float* hl = &h_lds[k & 1][0];                                         \
    float p0 = 0.f, p1 = 0.f, p2 = 0.f, p3 = 0.f;                               \
    const float4* h4 = (const float4*)(hl + seg * 68);                          \
    _Pragma("unroll")                                                           \
    for (int j = 0; j < 16; ++j) {                                              \
      float4 hv = h4[j];                                                        \
      p0 = fmaf(wreg[4 * j + 0], hv.x, p0);                                     \
      p1 = fmaf(wreg[4 * j + 1], hv.y, p1);                                     \
      p2 = fmaf(wreg[4 * j + 2], hv.z, p2);                                     \
      p3 = fmaf(wreg[4 * j + 3], hv.w, p3);                                     \
    }                                                                           \
    float p = (p0 + p1) + (p2 + p3) + xgv;                                      \
    p += __shfl_xor(p, 1);                                                      \
    p += __shfl_xor(p, 2);                                                      \
    p += __shfl_xor(p, 4);                                                      \
    float gb_ = __shfl_xor(p, 8);      /* gate g^1 */                           \
    float gc_ = __shfl_xor(p, 16);     /* gate g^2 */                           \
    float gd_ = __shfl_xor(gb_, 16);   /* gate g^3 */                           \
    if (g == 0) {                                                               \
      float iv = fsig(p), fv = fsig(gb_), ov = fsig(gd_);                       \
      float gv = ftanh(gc_);                                                    \
      c_reg = fv * c_reg + iv * gv;                                             \
      float hv = ov * ftanh(c_reg);                                             \
      if (seg == 0) {                                                           \
        ull pk = ((ull)(unsigned)(k + 2) << 32) | (ull)__float_as_uint(hv);     \
        __hip_atomic_store(&hb[((k + 1) & 1) * 512 + unit], pk,                 \
                           __ATOMIC_RELAXED, __HIP_MEMORY_SCOPE_AGENT);         \
        int orig = dir ? (S - 1 - k) : k;                                       \
        hs_cat[(size_t)orig * 1024 + dir * 512 + unit] = hv;                    \
      }                                                                         \
    }                                                                           \
  }

  for (int kk = 0; kk < S; kk += 2) {
    LSTM_STEP(kk, xg_a);
    LSTM_STEP(kk + 1, xg_b);
  }
  #undef LSTM_STEP
}

// ---------------- feats[t][j] = hs_cat[t] . Wout[j] + bout[j] ----------------
__global__ __launch_bounds__(64) void feats_k(
    const float* __restrict__ hs_cat, const float* __restrict__ Wout,
    const float* __restrict__ bout, float* __restrict__ feats)
{
  int tpos = blockIdx.x;
  int l = threadIdx.x;
  int j = l & 15, q = l >> 4;
  const float* h = hs_cat + (size_t)tpos * 1024 + q * 256;
  const float* wv = Wout + (size_t)j * 1024 + q * 256;
  float s = 0.f;
  #pragma unroll 8
  for (int i = 0; i < 256; i += 4) {
    float4 hv = *(const float4*)(h + i);
    float4 ww = *(const float4*)(wv + i);
    s = fmaf(hv.x, ww.x, s); s = fmaf(hv.y, ww.y, s);
    s = fmaf(hv.z, ww.z, s); s = fmaf(hv.w, ww.w, s);
  }
  s += __shfl_xor(s, 16);
  s += __shfl_xor(s, 32);
  if (q == 0) feats[tpos * 16 + j] = s + bout[j];
}

// ---------------- Viterbi: single wave, LDS-chunked feats, 4-bit backpointers ----------------
__global__ __launch_bounds__(64, 1) void viterbi_k(
    const float* __restrict__ feats, const float* __restrict__ trans,
    float* __restrict__ out)
{
  __shared__ __align__(16) float fch[2][256 * 16];  // 2 x 16KB double-buffer
  __shared__ unsigned char bp4[S * 8];              // 16KB packed nibbles
  __shared__ float v_lds[2][16];                    // double-buffered by step parity

  const int l = threadIdx.x;
  const int next = l & 15, q = l >> 4;

  float tr0 = trans[next * 16 + q * 4 + 0];
  float tr1 = trans[next * 16 + q * 4 + 1];
  float tr2 = trans[next * 16 + q * 4 + 2];
  float tr3 = trans[next * 16 + q * 4 + 3];

  if (l < 16) v_lds[0][l] = (l == 0) ? 0.0f : NEGV;   // START = 0

  const float4* f4 = (const float4*)feats;
  float4 buf[16];
  #pragma unroll
  for (int i = 0; i < 16; ++i) buf[i] = f4[i * 64 + l];
  #pragma unroll
  for (int i = 0; i < 16; ++i) ((float4*)fch[0])[i * 64 + l] = buf[i];
  __syncthreads();

  for (int c = 0; c < 8; ++c) {
    if (c < 7) {
      #pragma unroll
      for (int i = 0; i < 16; ++i) buf[i] = f4[(c + 1) * 1024 + i * 64 + l];
    }
    const float* fc = fch[c & 1];
    for (int tt = 0; tt < 256; ++tt) {
      int t = c * 256 + tt;
      int pb = t & 1;
      const float* vin = v_lds[pb];
      float m = vin[q * 4 + 0] + tr0; int mi = q * 4;
      float s1 = vin[q * 4 + 1] + tr1; if (s1 > m) { m = s1; mi = q * 4 + 1; }
      float s2 = vin[q * 4 + 2] + tr2; if (s2 > m) { m = s2; mi = q * 4 + 2; }
      float s3 = vin[q * 4 + 3] + tr3; if (s3 > m) { m = s3; mi = q * 4 + 3; }
      #pragma unroll
      for (int mask = 16; mask <= 32; mask <<= 1) {
        float om = __shfl_xor(m, mask);
        int omi = __shfl_xor(mi, mask);
        if (om > m || (om == m && omi < mi)) { m = om; mi = omi; }
      }
      int pmi = __shfl_xor(mi, 1);
      if (q == 0) {
        v_lds[pb ^ 1][next] = m + fc[tt * 16 + next];
        if ((next & 1) == 0)
          bp4[t * 8 + (next >> 1)] = (unsigned char)((mi & 15) | ((pmi & 15) << 4));
      }
      __syncthreads();   // one barrier per step (double-buffered v)
    }
    if (c < 7) {
      #pragma unroll
      for (int i = 0; i < 16; ++i) ((float4*)fch[(c + 1) & 1])[i * 64 + l] = buf[i];
      __syncthreads();
    }
  }

  // after t = S-1 (odd), final v is in v_lds[0]
  float term = (l < 16) ? (v_lds[0][l] + trans[1 * 16 + l]) : -3.0e38f;
  int ti = (l < 16) ? l : 0;
  #pragma unroll
  for (int mask = 1; mask <= 32; mask <<= 1) {
    float om = __shfl_xor(term, mask);
    int omi = __shfl_xor(ti, mask);
    if (om > term || (om == term && omi < ti)) { term = om; ti = omi; }
  }
  if (l == 0) {
    out[0] = term;
    int tag = ti;
    out[1 + (S - 1)] = (float)tag;
    for (int t = S - 1; t >= 1; --t) {
      tag = (bp4[t * 8 + (tag >> 1)] >> ((tag & 1) * 4)) & 15;
      out[t] = (float)tag;   // out[1 + (t-1)]
    }
  }
}

extern "C" void kernel_launch(void* const* d_in, const int* in_sizes, int n_in,
                              void* d_out, int out_size, void* d_ws, size_t ws_size,
                              hipStream_t stream) {
  const int*   sent  = (const int*)d_in[0];
  const float* emb   = (const float*)d_in[1];
  const float* Wih_f = (const float*)d_in[2];
  const float* Whh_f = (const float*)d_in[3];
  const float* bih_f = (const float*)d_in[4];
  const float* bhh_f = (const float*)d_in[5];
  const float* Wih_b = (const float*)d_in[6];
  const float* Whh_b = (const float*)d_in[7];
  const float* bih_b = (const float*)d_in[8];
  const float* bhh_b = (const float*)d_in[9];
  const float* h0    = (const float*)d_in[10];
  const float* c0    = (const float*)d_in[11];
  const float* Wout  = (const float*)d_in[12];
  const float* bout  = (const float*)d_in[13];
  const float* trans = (const float*)d_in[14];
  float* out = (float*)d_out;

  // workspace layout
  char* ws = (char*)d_ws;
  float* xg     = (float*)(ws);                         // 2048*4096*4 = 32 MiB
  float* hs_cat = (float*)(ws + 33554432);              // 2048*1024*4 = 8 MiB
  float* feats  = (float*)(ws + 41943040);              // 2048*16*4 = 128 KiB
  ull*   hbuf   = (ull*)  (ws + 42074112);              // 2*2*512*8 = 16 KiB
  int*   flags  = (int*)  (ws + 42090496);              // 32*64*4 = 8 KiB

  clear_flags_k<<<8, 256, 0, stream>>>(flags);
  init_h_k<<<2, 512, 0, stream>>>(h0, hbuf);
  fused_k<<<256, 256, 0, stream>>>(sent, emb, Wih_f, Wih_b, bih_f, bhh_f,
                                   bih_b, bhh_b, Whh_f, Whh_b, c0,
                                   xg, hbuf, hs_cat, flags);
  feats_k<<<2048, 64, 0, stream>>>(hs_cat, Wout, bout, feats);
  viterbi_k<<<1, 64, 0, stream>>>(feats, trans, out);
}